// Round 6
// baseline (2367.951 us; speedup 1.0000x reference)
//
#include <hip/hip_runtime.h>
#include <math.h>

#define BS   2
#define NPC  16384
#define NQ   1024
#define KNN  20
#define D    128
#define NH   8
#define HD   16
#define DFF  2048
#define NL   3
#define NSEQ (BS*NQ)   // 2048 sequences
#define EPS  1e-5f
#define PAD  132

typedef __attribute__((ext_vector_type(8))) short bf16x8;
typedef __attribute__((ext_vector_type(4))) float f32x4;
#define MFMA_BF16 __builtin_amdgcn_mfma_f32_16x16x32_bf16

__device__ __forceinline__ unsigned short f2bf(float v) {
    union { float f; unsigned u; } x; x.f = v;
    unsigned r = x.u + 0x7FFFu + ((x.u >> 16) & 1u);
    return (unsigned short)(r >> 16);
}
__device__ __forceinline__ float bf2f(unsigned short h) {
    union { unsigned u; float f; } x; x.u = ((unsigned)h) << 16;
    return x.f;
}

// ---------------------------------------------------------------------------
// KNN: one wave per query; register top-20 + shuffle tournament (unchanged).
// ---------------------------------------------------------------------------
__global__ __launch_bounds__(256) void knn_kernel(
    const float* __restrict__ pc, const float* __restrict__ query,
    int* __restrict__ idx_out, float* __restrict__ dis_out)
{
    int wave = threadIdx.x >> 6;
    int lane = threadIdx.x & 63;
    int g = blockIdx.x * 4 + wave;
    int b = g >> 10;
    int q = g & (NQ - 1);

    const float* qp = query + ((size_t)b * NQ + q) * 3;
    float qx = qp[0], qy = qp[1], qz = qp[2];
    float qq = qx*qx + qy*qy + qz*qz;

    float bd[KNN]; int bi[KNN];
#pragma unroll
    for (int i = 0; i < KNN; ++i) { bd[i] = 3.0e38f; bi[i] = -1; }

    const float* pcb = pc + (size_t)b * NPC * 3;
    for (int p = lane; p < NPC; p += 64) {
        float px = pcb[p*3+0], py = pcb[p*3+1], pz = pcb[p*3+2];
        float pp = px*px + py*py + pz*pz;
        float d2 = qq + pp - 2.0f*(qx*px + qy*py + qz*pz);
        if (d2 < bd[KNN-1]) {
#pragma unroll
            for (int j = KNN-1; j >= 1; --j) {
                bool sh = bd[j-1] > d2;
                bool tk = bd[j]   > d2;
                float nv = sh ? bd[j-1] : (tk ? d2 : bd[j]);
                int   ni = sh ? bi[j-1] : (tk ? p  : bi[j]);
                bd[j] = nv; bi[j] = ni;
            }
            bool tk0 = bd[0] > d2;
            bi[0] = tk0 ? p  : bi[0];
            bd[0] = tk0 ? d2 : bd[0];
        }
    }

    float outd = 0.f; int outi = 0;
    for (int r = 0; r < KNN; ++r) {
        float mv = bd[0]; int mi = bi[0];
#pragma unroll
        for (int o = 32; o > 0; o >>= 1) {
            float ov = __shfl_xor(mv, o);
            int   oi = __shfl_xor(mi, o);
            if (ov < mv || (ov == mv && oi < mi)) { mv = ov; mi = oi; }
        }
        if (lane == r) { outd = mv; outi = mi; }
        if (bi[0] == mi) {
#pragma unroll
            for (int j = 0; j < KNN-1; ++j) { bd[j] = bd[j+1]; bi[j] = bi[j+1]; }
            bd[KNN-1] = 3.4e38f; bi[KNN-1] = -1;
        }
    }
    if (lane < KNN) {
        dis_out[g*KNN + lane] = sqrtf(fmaxf(outd, 0.f));
        idx_out[g*KNN + lane] = outi;
    }
}

// ---------------------------------------------------------------------------
// Gather + context modulation (unchanged).
// ---------------------------------------------------------------------------
__global__ __launch_bounds__(256) void pool_kernel(
    const float* __restrict__ x, const float* __restrict__ pc,
    const float* __restrict__ query,
    const float* __restrict__ ckw, const float* __restrict__ ckb,
    const float* __restrict__ cbw, const float* __restrict__ cbb,
    const int* __restrict__ idx, const float* __restrict__ dis,
    float* __restrict__ h)
{
    int g = blockIdx.x; int b = g >> 10; int q = g & (NQ-1);
    int d = threadIdx.x & 127;
    int half = threadIdx.x >> 7;
    const float* qp = query + ((size_t)b*NQ + q)*3;
    float qx = qp[0], qy = qp[1], qz = qp[2];
    float kw[7], bw[7];
#pragma unroll
    for (int j = 0; j < 7; ++j) { kw[j] = ckw[d*7+j]; bw[j] = cbw[d*7+j]; }
    float kb = ckb[d], bb = cbb[d];
    for (int jj = 0; jj < 10; ++jj) {
        int k = half*10 + jj;
        int p = idx[g*KNN + k];
        float dd = dis[g*KNN + k];
        const float* pr = pc + ((size_t)b*NPC + p)*3;
        float c1 = pr[0], c2 = pr[1], c3 = pr[2];
        float scale = kb + kw[0]*dd + kw[1]*c1 + kw[2]*c2 + kw[3]*c3
                         + kw[4]*qx + kw[5]*qy + kw[6]*qz;
        float shift = bb + bw[0]*dd + bw[1]*c1 + bw[2]*c2 + bw[3]*c3
                         + bw[4]*qx + bw[5]*qy + bw[6]*qz;
        float xv = x[((size_t)b*NPC + p)*D + d];
        h[((size_t)g*KNN + k)*D + d] = xv*scale + shift;
    }
}

// ---------------------------------------------------------------------------
// Weight pre-split: fp32 -> (hi, lo) bf16, RNE both stages.  Runs every call.
// ---------------------------------------------------------------------------
__global__ __launch_bounds__(256) void prep_kernel(
    const float* __restrict__ w1, const float* __restrict__ w2,
    unsigned short* __restrict__ w1h, unsigned short* __restrict__ w1l,
    unsigned short* __restrict__ w2h, unsigned short* __restrict__ w2l)
{
    int i = blockIdx.x * 256 + threadIdx.x;
    if (i < NL*DFF*D) {
        float a = w1[i];
        unsigned short ah = f2bf(a);
        w1h[i] = ah; w1l[i] = f2bf(a - bf2f(ah));
        float b = w2[i];
        unsigned short bh = f2bf(b);
        w2h[i] = bh; w2l[i] = f2bf(b - bf2f(bh));
    }
}

// ---------------------------------------------------------------------------
// Attention half-layer (unchanged fp32).
// ---------------------------------------------------------------------------
__global__ __launch_bounds__(256) void attn_kernel(
    float* __restrict__ h,
    const float* __restrict__ w_in, const float* __restrict__ b_in,
    const float* __restrict__ w_out, const float* __restrict__ b_out,
    const float* __restrict__ g1, const float* __restrict__ bb1,
    int layer)
{
    __shared__ float hs[KNN][PAD];
    __shared__ float qs[KNN][PAD];
    __shared__ float ks[KNN][PAD];
    __shared__ float vs[KNN][PAD];
    __shared__ float os[KNN][PAD];
    __shared__ float mu_s[KNN], rs_s[KNN];

    int tid = threadIdx.x;
    size_t base = (size_t)blockIdx.x * KNN * D;
    for (int i = tid; i < KNN*D; i += 256) hs[i>>7][i&127] = h[base + i];
    __syncthreads();

    {
        int cg = tid & 63;
        int tg = tid >> 6;
        const float* W = w_in + (size_t)layer*3*D*D;
        const float* B = b_in + (size_t)layer*3*D;
        float acc[5][6];
#pragma unroll
        for (int ci = 0; ci < 6; ++ci) {
            float bv = B[cg*6 + ci];
#pragma unroll
            for (int ti = 0; ti < 5; ++ti) acc[ti][ci] = bv;
        }
        for (int cc = 0; cc < D; cc += 4) {
            float4 hv[5];
#pragma unroll
            for (int ti = 0; ti < 5; ++ti)
                hv[ti] = *(const float4*)&hs[tg*5+ti][cc];
#pragma unroll
            for (int ci = 0; ci < 6; ++ci) {
                float4 wv = *(const float4*)&W[(size_t)(cg*6+ci)*D + cc];
#pragma unroll
                for (int ti = 0; ti < 5; ++ti)
                    acc[ti][ci] += hv[ti].x*wv.x + hv[ti].y*wv.y
                                 + hv[ti].z*wv.z + hv[ti].w*wv.w;
            }
        }
#pragma unroll
        for (int ci = 0; ci < 6; ++ci) {
            int c = cg*6 + ci;
#pragma unroll
            for (int ti = 0; ti < 5; ++ti) {
                int t = tg*5 + ti;
                float v = acc[ti][ci];
                if (c < D)        qs[t][c]       = v;
                else if (c < 2*D) ks[t][c-D]     = v;
                else              vs[t][c-2*D]   = v;
            }
        }
    }
    __syncthreads();

    if (tid < NH*KNN) {
        int hh = tid / KNN;
        int t1 = tid % KNN;
        int c0 = hh * HD;
        float a[KNN];
        float mx = -3.4e38f;
#pragma unroll
        for (int t2 = 0; t2 < KNN; ++t2) {
            float s = 0.f;
#pragma unroll
            for (int dd = 0; dd < HD; ++dd) s += qs[t1][c0+dd]*ks[t2][c0+dd];
            s *= 0.25f;
            a[t2] = s;
            mx = fmaxf(mx, s);
        }
        float sum = 0.f;
#pragma unroll
        for (int t2 = 0; t2 < KNN; ++t2) { a[t2] = expf(a[t2]-mx); sum += a[t2]; }
        float inv = 1.0f / sum;
#pragma unroll
        for (int dd = 0; dd < HD; ++dd) {
            float o = 0.f;
#pragma unroll
            for (int t2 = 0; t2 < KNN; ++t2) o += a[t2]*vs[t2][c0+dd];
            os[t1][c0+dd] = o * inv;
        }
    }
    __syncthreads();

    {
        int d = tid & 127;
        int tg = tid >> 7;
        const float* W = w_out + ((size_t)layer*D + d)*D;
        float acc[10];
        float bo = b_out[layer*D + d];
#pragma unroll
        for (int ti = 0; ti < 10; ++ti) acc[ti] = bo;
        for (int c = 0; c < D; c += 4) {
            float4 wv = *(const float4*)&W[c];
#pragma unroll
            for (int ti = 0; ti < 10; ++ti) {
                float4 ov = *(const float4*)&os[tg*10+ti][c];
                acc[ti] += ov.x*wv.x + ov.y*wv.y + ov.z*wv.z + ov.w*wv.w;
            }
        }
#pragma unroll
        for (int ti = 0; ti < 10; ++ti) hs[tg*10+ti][d] += acc[ti];
    }
    __syncthreads();

    if (tid < KNN*8) {
        int t = tid >> 3, j = tid & 7;
        float s = 0.f;
#pragma unroll
        for (int cc = 0; cc < 16; cc += 4) {
            float4 v = *(const float4*)&hs[t][j*16 + cc];
            s += v.x + v.y + v.z + v.w;
        }
#pragma unroll
        for (int o = 1; o < 8; o <<= 1) s += __shfl_xor(s, o);
        float mu = s * (1.0f/D);
        float vv = 0.f;
#pragma unroll
        for (int cc = 0; cc < 16; cc += 4) {
            float4 v = *(const float4*)&hs[t][j*16 + cc];
            float a0 = v.x-mu, a1 = v.y-mu, a2 = v.z-mu, a3 = v.w-mu;
            vv += a0*a0 + a1*a1 + a2*a2 + a3*a3;
        }
#pragma unroll
        for (int o = 1; o < 8; o <<= 1) vv += __shfl_xor(vv, o);
        if (j == 0) {
            mu_s[t] = mu;
            rs_s[t] = rsqrtf(vv*(1.0f/D) + EPS);
        }
    }
    __syncthreads();
    for (int i = tid; i < KNN*D; i += 256) {
        int t = i >> 7, c = i & 127;
        h[base + i] = (hs[t][c]-mu_s[t])*rs_s[t]*g1[layer*D+c] + bb1[layer*D+c];
    }
}

// ---------------------------------------------------------------------------
// FFN via split-bf16 MFMA (3-term, fp32-grade accuracy).
// Block = 64 tokens (FFN is per-token; seq boundaries irrelevant), 4 waves.
// N-split: wave owns 16 f-cols (GEMM1) / 32 d-cols (GEMM2) so each W tile is
// loaded exactly once per block.  h and ft staged hi/lo in XOR-swizzled LDS.
// A-frag: row=lane&15, k=(lane>>4)*8+i (contiguous k).  B-frag: col=lane&15,
// same k packing.  C/D: col=lane&15, row=(lane>>4)*4+reg (m89-verified).
// ---------------------------------------------------------------------------
#define TOKB 64
__global__ __launch_bounds__(256) void ffn_mfma_kernel(
    float* __restrict__ h,
    const unsigned short* __restrict__ w1h, const unsigned short* __restrict__ w1l,
    const unsigned short* __restrict__ w2h, const unsigned short* __restrict__ w2l,
    const float* __restrict__ b1, const float* __restrict__ b2,
    const float* __restrict__ g2, const float* __restrict__ bb2,
    int layer)
{
    __shared__ __align__(16) unsigned char smem[49152];
    unsigned short* hhi = (unsigned short*)smem;       // [64][128] bf16 swz
    unsigned short* hlo = hhi + 64*128;
    unsigned short* fhi = hlo + 64*128;                // [64][64] bf16 swz
    unsigned short* flo = fhi + 64*64;
    float* hsf = (float*)smem;                         // [64][132] f32 (epilogue reuse)

    int tid = threadIdx.x;
    int lane = tid & 63, wv = tid >> 6;
    int l16 = lane & 15, g16 = lane >> 4;
    size_t base = (size_t)blockIdx.x * (TOKB * D);

    // ---- stage h -> split hi/lo bf16, XOR-swizzled rows
#pragma unroll
    for (int e = 0; e < 8; ++e) {
        int flat4 = tid + e*256;              // 2048 float4 chunks
        int t = flat4 >> 5;
        int c = (flat4 & 31) << 2;
        float4 v = *(const float4*)&h[base + (size_t)t*D + c];
        unsigned short h0=f2bf(v.x), h1=f2bf(v.y), h2=f2bf(v.z), h3=f2bf(v.w);
        unsigned short l0=f2bf(v.x-bf2f(h0)), l1=f2bf(v.y-bf2f(h1)),
                       l2=f2bf(v.z-bf2f(h2)), l3=f2bf(v.w-bf2f(h3));
        int idx = t*128 + (c ^ ((t & 7) << 3));   // c mult of 4 -> stays aligned
        unsigned long long ph = (unsigned long long)h0 | ((unsigned long long)h1<<16)
                              | ((unsigned long long)h2<<32) | ((unsigned long long)h3<<48);
        unsigned long long pl = (unsigned long long)l0 | ((unsigned long long)l1<<16)
                              | ((unsigned long long)l2<<32) | ((unsigned long long)l3<<48);
        *(unsigned long long*)&hhi[idx] = ph;
        *(unsigned long long*)&hlo[idx] = pl;
    }
    __syncthreads();

    const unsigned short* W1h = w1h + (size_t)layer*DFF*D;
    const unsigned short* W1l = w1l + (size_t)layer*DFF*D;
    const unsigned short* W2h = w2h + (size_t)layer*D*DFF;
    const unsigned short* W2l = w2l + (size_t)layer*D*DFF;

    int myf = wv*16 + l16;                    // this lane's f within the 64-tile

    f32x4 acc2[4][2];
#pragma unroll
    for (int m = 0; m < 4; ++m)
#pragma unroll
        for (int j = 0; j < 2; ++j) acc2[m][j] = (f32x4){0.f,0.f,0.f,0.f};

    for (int ft0 = 0; ft0 < DFF; ft0 += 64) {
        float b1v = b1[layer*DFF + ft0 + myf];
        // W1 b-frags for my 16 f-cols: [kk][hi|lo], loaded once
        bf16x8 b1f[4][2];
        {
            const unsigned short* r1h = W1h + (size_t)(ft0 + myf)*D + g16*8;
            const unsigned short* r1l = W1l + (size_t)(ft0 + myf)*D + g16*8;
#pragma unroll
            for (int kk = 0; kk < 4; ++kk) {
                b1f[kk][0] = *(const bf16x8*)(r1h + kk*32);
                b1f[kk][1] = *(const bf16x8*)(r1l + kk*32);
            }
        }
        // GEMM1: out1[64 tok][my 16 f] = h @ W1^T (3-term split)
        f32x4 acc1[4];
#pragma unroll
        for (int m = 0; m < 4; ++m) acc1[m] = (f32x4){0.f,0.f,0.f,0.f};
#pragma unroll
        for (int m = 0; m < 4; ++m) {
            int arow = m*16 + l16;
            int asw = (arow & 7) << 3;
#pragma unroll
            for (int kk = 0; kk < 4; ++kk) {
                int cc = kk*32 + g16*8;
                int idx = arow*128 + (cc ^ asw);
                bf16x8 ah = *(const bf16x8*)&hhi[idx];
                bf16x8 al = *(const bf16x8*)&hlo[idx];
                acc1[m] = MFMA_BF16(ah, b1f[kk][0], acc1[m], 0, 0, 0);
                acc1[m] = MFMA_BF16(ah, b1f[kk][1], acc1[m], 0, 0, 0);
                acc1[m] = MFMA_BF16(al, b1f[kk][0], acc1[m], 0, 0, 0);
            }
        }
        __syncthreads();    // previous tile's GEMM2 reads of ft are done
        // bias + relu + split -> ft  (D layout: row=(g16)*4+r, col=l16-based)
#pragma unroll
        for (int m = 0; m < 4; ++m) {
#pragma unroll
            for (int r = 0; r < 4; ++r) {
                int t = m*16 + g16*4 + r;
                float val = fmaxf(acc1[m][r] + b1v, 0.f);
                unsigned short vh = f2bf(val);
                unsigned short vl = f2bf(val - bf2f(vh));
                int idx = t*64 + (myf ^ ((t & 7) << 3));
                fhi[idx] = vh;
                flo[idx] = vl;
            }
        }
        __syncthreads();
        // W2 b-frags for my 32 d-cols: [j][kk2][hi|lo]
        bf16x8 b2f[2][2][2];
#pragma unroll
        for (int j = 0; j < 2; ++j) {
            int d = wv*32 + j*16 + l16;
            const unsigned short* r2h = W2h + (size_t)d*DFF + ft0 + g16*8;
            const unsigned short* r2l = W2l + (size_t)d*DFF + ft0 + g16*8;
#pragma unroll
            for (int kk2 = 0; kk2 < 2; ++kk2) {
                b2f[j][kk2][0] = *(const bf16x8*)(r2h + kk2*32);
                b2f[j][kk2][1] = *(const bf16x8*)(r2l + kk2*32);
            }
        }
        // GEMM2: acc2 += ft @ W2^T over this 64-wide f chunk
#pragma unroll
        for (int m = 0; m < 4; ++m) {
            int arow = m*16 + l16;
            int asw = (arow & 7) << 3;
#pragma unroll
            for (int kk2 = 0; kk2 < 2; ++kk2) {
                int fo = kk2*32 + g16*8;
                int idx = arow*64 + (fo ^ asw);
                bf16x8 ah = *(const bf16x8*)&fhi[idx];
                bf16x8 al = *(const bf16x8*)&flo[idx];
#pragma unroll
                for (int j = 0; j < 2; ++j) {
                    acc2[m][j] = MFMA_BF16(ah, b2f[j][kk2][0], acc2[m][j], 0, 0, 0);
                    acc2[m][j] = MFMA_BF16(ah, b2f[j][kk2][1], acc2[m][j], 0, 0, 0);
                    acc2[m][j] = MFMA_BF16(al, b2f[j][kk2][0], acc2[m][j], 0, 0, 0);
                }
            }
        }
    }

    // ---- epilogue: +b2 + residual (hi+lo reconstruct), LN2, store
    float val[4][2][4];
#pragma unroll
    for (int j = 0; j < 2; ++j) {
        int d = wv*32 + j*16 + l16;
        float bb = b2[layer*D + d];
#pragma unroll
        for (int m = 0; m < 4; ++m) {
#pragma unroll
            for (int r = 0; r < 4; ++r) {
                int t = m*16 + g16*4 + r;
                int idx = t*128 + (d ^ ((t & 7) << 3));
                float res = bf2f(hhi[idx]) + bf2f(hlo[idx]);
                val[m][j][r] = acc2[m][j][r] + bb + res;
            }
        }
    }
    __syncthreads();                 // all residual reads done before LDS reuse
#pragma unroll
    for (int j = 0; j < 2; ++j) {
        int d = wv*32 + j*16 + l16;
#pragma unroll
        for (int m = 0; m < 4; ++m)
#pragma unroll
            for (int r = 0; r < 4; ++r) {
                int t = m*16 + g16*4 + r;
                hsf[t*132 + d] = val[m][j][r];
            }
    }
    __syncthreads();
    {   // LN2: 4 threads per token, 32 d each
        int tt = tid >> 2, part = tid & 3;
        const float* row = &hsf[tt*132 + part*32];
        float s = 0.f;
#pragma unroll
        for (int i = 0; i < 32; i += 4) {
            float4 v4 = *(const float4*)&row[i];
            s += v4.x + v4.y + v4.z + v4.w;
        }
        s += __shfl_xor(s, 1); s += __shfl_xor(s, 2);
        float mu = s * (1.f/128.f);
        float vv = 0.f;
#pragma unroll
        for (int i = 0; i < 32; i += 4) {
            float4 v4 = *(const float4*)&row[i];
            float a0 = v4.x-mu, a1 = v4.y-mu, a2 = v4.z-mu, a3 = v4.w-mu;
            vv += a0*a0 + a1*a1 + a2*a2 + a3*a3;
        }
        vv += __shfl_xor(vv, 1); vv += __shfl_xor(vv, 2);
        float rs = rsqrtf(vv*(1.f/128.f) + EPS);
        const float* G  = g2  + layer*D + part*32;
        const float* Bt = bb2 + layer*D + part*32;
        float* O = &h[base + (size_t)tt*D + part*32];
#pragma unroll
        for (int i = 0; i < 32; i += 4) {
            float4 v4 = *(const float4*)&row[i];
            float4 gg = *(const float4*)&G[i];
            float4 bt = *(const float4*)&Bt[i];
            float4 o;
            o.x = (v4.x-mu)*rs*gg.x + bt.x;
            o.y = (v4.y-mu)*rs*gg.y + bt.y;
            o.z = (v4.z-mu)*rs*gg.z + bt.z;
            o.w = (v4.w-mu)*rs*gg.w + bt.w;
            *(float4*)&O[i] = o;
        }
    }
}

// ---------------------------------------------------------------------------
// Final linear (unchanged).
// ---------------------------------------------------------------------------
__global__ __launch_bounds__(256) void final_kernel(
    const float* __restrict__ h, const float* __restrict__ lw,
    const float* __restrict__ lb, float* __restrict__ out)
{
    __shared__ float hr[4][KNN*D];
    int g0 = blockIdx.x * 4;
    int tid = threadIdx.x;
    for (int i = tid; i < 4*KNN*D; i += 256)
        hr[i / (KNN*D)][i % (KNN*D)] = h[(size_t)g0*KNN*D + i];
    __syncthreads();

    int d = tid & 127;
    int s = tid >> 7;
    const float* W = lw + (size_t)d * (KNN*D);
    float acc0 = lb[d], acc1 = lb[d];
#pragma unroll 4
    for (int j = 0; j < KNN*D; j += 4) {
        float4 wv = *(const float4*)&W[j];
        float4 h0 = *(const float4*)&hr[s][j];
        float4 h1 = *(const float4*)&hr[s+2][j];
        acc0 += h0.x*wv.x + h0.y*wv.y + h0.z*wv.z + h0.w*wv.w;
        acc1 += h1.x*wv.x + h1.y*wv.y + h1.z*wv.z + h1.w*wv.w;
    }
    out[(size_t)(g0+s)*D + d]   = acc0;
    out[(size_t)(g0+s+2)*D + d] = acc1;
}

// ---------------------------------------------------------------------------
extern "C" void kernel_launch(void* const* d_in, const int* in_sizes, int n_in,
                              void* d_out, int out_size, void* d_ws, size_t ws_size,
                              hipStream_t stream)
{
    const float* x     = (const float*)d_in[0];
    const float* pc    = (const float*)d_in[1];
    const float* query = (const float*)d_in[2];
    const float* ckw   = (const float*)d_in[3];
    const float* ckb   = (const float*)d_in[4];
    const float* cbw   = (const float*)d_in[5];
    const float* cbb   = (const float*)d_in[6];
    const float* w_in  = (const float*)d_in[7];
    const float* b_in  = (const float*)d_in[8];
    const float* w_out = (const float*)d_in[9];
    const float* b_out = (const float*)d_in[10];
    const float* w1    = (const float*)d_in[11];
    const float* b1    = (const float*)d_in[12];
    const float* w2    = (const float*)d_in[13];
    const float* b2    = (const float*)d_in[14];
    const float* g1    = (const float*)d_in[15];
    const float* bb1   = (const float*)d_in[16];
    const float* g2    = (const float*)d_in[17];
    const float* bb2   = (const float*)d_in[18];
    const float* lw    = (const float*)d_in[19];
    const float* lb    = (const float*)d_in[20];
    float* out = (float*)d_out;

    char* ws = (char*)d_ws;
    int*   idx = (int*)ws;                                   // 2048*20 int
    float* dis = (float*)(ws + 163840);                      // 2048*20 f32
    float* h   = (float*)(ws + 327680);                      // 40960*128 f32 (~21 MB)
    unsigned short* w1hp = (unsigned short*)(ws + 21299200);             // 1.5 MB each
    unsigned short* w1lp = (unsigned short*)(ws + 21299200 + 1572864);
    unsigned short* w2hp = (unsigned short*)(ws + 21299200 + 2*1572864);
    unsigned short* w2lp = (unsigned short*)(ws + 21299200 + 3*1572864);

    knn_kernel <<<NSEQ/4, 256, 0, stream>>>(pc, query, idx, dis);
    pool_kernel<<<NSEQ,   256, 0, stream>>>(x, pc, query, ckw, ckb, cbw, cbb,
                                            idx, dis, h);
    prep_kernel<<<(NL*DFF*D)/256, 256, 0, stream>>>(w1, w2, w1hp, w1lp, w2hp, w2lp);
    for (int l = 0; l < NL; ++l) {
        attn_kernel<<<NSEQ, 256, 0, stream>>>(h, w_in, b_in, w_out, b_out,
                                              g1, bb1, l);
        ffn_mfma_kernel<<<(NSEQ*KNN)/TOKB, 256, 0, stream>>>(
            h, w1hp, w1lp, w2hp, w2lp, b1, b2, g2, bb2, l);
    }
    final_kernel<<<NSEQ/4, 256, 0, stream>>>(h, lw, lb, out);
}

// Round 12
// 1475.431 us; speedup vs baseline: 1.6049x; 1.6049x over previous
//
#include <hip/hip_runtime.h>
#include <math.h>

#define BS   2
#define NPC  16384
#define NQ   1024
#define KNN  20
#define D    128
#define NH   8
#define HD   16
#define DFF  2048
#define NL   3
#define NSEQ (BS*NQ)
#define EPS  1e-5f
#define PAD  132

typedef __attribute__((ext_vector_type(8))) short bf16x8;
typedef __attribute__((ext_vector_type(4))) float f32x4;
#define MFMA_BF16 __builtin_amdgcn_mfma_f32_16x16x32_bf16

__device__ __forceinline__ unsigned short f2bf(float v) {
    union { float f; unsigned u; } x; x.f = v;
    unsigned r = x.u + 0x7FFFu + ((x.u >> 16) & 1u);
    return (unsigned short)(r >> 16);
}
__device__ __forceinline__ float bf2f(unsigned short h) {
    union { unsigned u; float f; } x; x.u = ((unsigned)h) << 16;
    return x.f;
}
__device__ __forceinline__ bf16x8 pack8(const float* v) {
    bf16x8 r;
#pragma unroll
    for (int i = 0; i < 8; ++i) r[i] = (short)f2bf(v[i]);
    return r;
}

// ---------------------------------------------------------------------------
// KNN (unchanged, validated).
// ---------------------------------------------------------------------------
__global__ __launch_bounds__(256) void knn_kernel(
    const float* __restrict__ pc, const float* __restrict__ query,
    int* __restrict__ idx_out, float* __restrict__ dis_out)
{
    int wave = threadIdx.x >> 6;
    int lane = threadIdx.x & 63;
    int g = blockIdx.x * 4 + wave;
    int b = g >> 10;
    int q = g & (NQ - 1);

    const float* qp = query + ((size_t)b * NQ + q) * 3;
    float qx = qp[0], qy = qp[1], qz = qp[2];
    float qq = qx*qx + qy*qy + qz*qz;

    float bd[KNN]; int bi[KNN];
#pragma unroll
    for (int i = 0; i < KNN; ++i) { bd[i] = 3.0e38f; bi[i] = -1; }

    const float* pcb = pc + (size_t)b * NPC * 3;
    for (int p = lane; p < NPC; p += 64) {
        float px = pcb[p*3+0], py = pcb[p*3+1], pz = pcb[p*3+2];
        float pp = px*px + py*py + pz*pz;
        float d2 = qq + pp - 2.0f*(qx*px + qy*py + qz*pz);
        if (d2 < bd[KNN-1]) {
#pragma unroll
            for (int j = KNN-1; j >= 1; --j) {
                bool sh = bd[j-1] > d2;
                bool tk = bd[j]   > d2;
                float nv = sh ? bd[j-1] : (tk ? d2 : bd[j]);
                int   ni = sh ? bi[j-1] : (tk ? p  : bi[j]);
                bd[j] = nv; bi[j] = ni;
            }
            bool tk0 = bd[0] > d2;
            bi[0] = tk0 ? p  : bi[0];
            bd[0] = tk0 ? d2 : bd[0];
        }
    }

    float outd = 0.f; int outi = 0;
    for (int r = 0; r < KNN; ++r) {
        float mv = bd[0]; int mi = bi[0];
#pragma unroll
        for (int o = 32; o > 0; o >>= 1) {
            float ov = __shfl_xor(mv, o);
            int   oi = __shfl_xor(mi, o);
            if (ov < mv || (ov == mv && oi < mi)) { mv = ov; mi = oi; }
        }
        if (lane == r) { outd = mv; outi = mi; }
        if (bi[0] == mi) {
#pragma unroll
            for (int j = 0; j < KNN-1; ++j) { bd[j] = bd[j+1]; bi[j] = bi[j+1]; }
            bd[KNN-1] = 3.4e38f; bi[KNN-1] = -1;
        }
    }
    if (lane < KNN) {
        dis_out[g*KNN + lane] = sqrtf(fmaxf(outd, 0.f));
        idx_out[g*KNN + lane] = outi;
    }
}

// ---------------------------------------------------------------------------
// Gather + context modulation (unchanged, validated).
// ---------------------------------------------------------------------------
__global__ __launch_bounds__(256) void pool_kernel(
    const float* __restrict__ x, const float* __restrict__ pc,
    const float* __restrict__ query,
    const float* __restrict__ ckw, const float* __restrict__ ckb,
    const float* __restrict__ cbw, const float* __restrict__ cbb,
    const int* __restrict__ idx, const float* __restrict__ dis,
    float* __restrict__ h)
{
    int g = blockIdx.x; int b = g >> 10; int q = g & (NQ-1);
    int d = threadIdx.x & 127;
    int half = threadIdx.x >> 7;
    const float* qp = query + ((size_t)b*NQ + q)*3;
    float qx = qp[0], qy = qp[1], qz = qp[2];
    float kw[7], bw[7];
#pragma unroll
    for (int j = 0; j < 7; ++j) { kw[j] = ckw[d*7+j]; bw[j] = cbw[d*7+j]; }
    float kb = ckb[d], bb = cbb[d];
    for (int jj = 0; jj < 10; ++jj) {
        int k = half*10 + jj;
        int p = idx[g*KNN + k];
        float dd = dis[g*KNN + k];
        const float* pr = pc + ((size_t)b*NPC + p)*3;
        float c1 = pr[0], c2 = pr[1], c3 = pr[2];
        float scale = kb + kw[0]*dd + kw[1]*c1 + kw[2]*c2 + kw[3]*c3
                         + kw[4]*qx + kw[5]*qy + kw[6]*qz;
        float shift = bb + bw[0]*dd + bw[1]*c1 + bw[2]*c2 + bw[3]*c3
                         + bw[4]*qx + bw[5]*qy + bw[6]*qz;
        float xv = x[((size_t)b*NPC + p)*D + d];
        h[((size_t)g*KNN + k)*D + d] = xv*scale + shift;
    }
}

// ---------------------------------------------------------------------------
// Weight pre-split: fp32 -> (hi, lo) bf16 for w1, w2, w_in, w_out.
// ---------------------------------------------------------------------------
__global__ __launch_bounds__(256) void prep_kernel(
    const float* __restrict__ w1, const float* __restrict__ w2,
    const float* __restrict__ wi, const float* __restrict__ wo,
    unsigned short* __restrict__ w1h, unsigned short* __restrict__ w1l,
    unsigned short* __restrict__ w2h, unsigned short* __restrict__ w2l,
    unsigned short* __restrict__ wih, unsigned short* __restrict__ wil,
    unsigned short* __restrict__ woh, unsigned short* __restrict__ wol)
{
    int i = blockIdx.x * 256 + threadIdx.x;
    if (i < NL*DFF*D) {
        float a = w1[i];
        unsigned short ah = f2bf(a);
        w1h[i] = ah; w1l[i] = f2bf(a - bf2f(ah));
        float b = w2[i];
        unsigned short bh = f2bf(b);
        w2h[i] = bh; w2l[i] = f2bf(b - bf2f(bh));
    }
    if (i < NL*3*D*D) {
        float a = wi[i];
        unsigned short ah = f2bf(a);
        wih[i] = ah; wil[i] = f2bf(a - bf2f(ah));
    }
    if (i < NL*D*D) {
        float a = wo[i];
        unsigned short ah = f2bf(a);
        woh[i] = ah; wol[i] = f2bf(a - bf2f(ah));
    }
}

// ---------------------------------------------------------------------------
// Attention half-layer via split-bf16 MFMA.  One block = 1 sequence, 4 waves.
// QKV: M=32(pad), N=384 (wave owns 96 cols = 6 N-tiles), K=128.
// out-proj: N=128 (wave owns 32 cols), A = os split on the fly.
// Fragment layouts identical to validated ffn_mfma_kernel.
// ---------------------------------------------------------------------------
__global__ __launch_bounds__(256) void attn_mfma_kernel(
    float* __restrict__ h,
    const unsigned short* __restrict__ wih, const unsigned short* __restrict__ wil,
    const unsigned short* __restrict__ woh, const unsigned short* __restrict__ wol,
    const float* __restrict__ b_in, const float* __restrict__ b_out,
    const float* __restrict__ g1, const float* __restrict__ bb1,
    int layer)
{
    __shared__ __align__(16) unsigned short hhi[32*128];   // 8 KB, swizzled
    __shared__ __align__(16) unsigned short hlo[32*128];   // 8 KB
    __shared__ __align__(16) float qkv[20*388];            // 30.3 KB  q|k|v
    __shared__ __align__(16) float os[32*132];             // 16.5 KB  (rows 20-31 zero)
    __shared__ float mu_s[KNN], rs_s[KNN];

    int tid = threadIdx.x;
    int lane = tid & 63, wv = tid >> 6;
    int l16 = lane & 15, g16 = lane >> 4;
    size_t base = (size_t)blockIdx.x * (KNN * D);

    // ---- stage h -> hi/lo bf16 swizzled; zero pad rows; zero os pad rows
    for (int i = tid; i < 640; i += 256) {            // 20 rows x 32 float4
        int t = i >> 5, c = (i & 31) << 2;
        float4 v = *(const float4*)&h[base + (size_t)t*D + c];
        unsigned short h0=f2bf(v.x), h1=f2bf(v.y), h2=f2bf(v.z), h3=f2bf(v.w);
        unsigned short l0=f2bf(v.x-bf2f(h0)), l1=f2bf(v.y-bf2f(h1)),
                       l2=f2bf(v.z-bf2f(h2)), l3=f2bf(v.w-bf2f(h3));
        int idx = t*128 + (c ^ ((t & 7) << 3));
        unsigned long long ph = (unsigned long long)h0 | ((unsigned long long)h1<<16)
                              | ((unsigned long long)h2<<32) | ((unsigned long long)h3<<48);
        unsigned long long pl = (unsigned long long)l0 | ((unsigned long long)l1<<16)
                              | ((unsigned long long)l2<<32) | ((unsigned long long)l3<<48);
        *(unsigned long long*)&hhi[idx] = ph;
        *(unsigned long long*)&hlo[idx] = pl;
    }
    for (int i = tid; i < 384; i += 256) {            // rows 20-31 zero (12 x 32 f4)
        int t = 20 + (i >> 5), c = (i & 31) << 2;
        int idx = t*128 + (c ^ ((t & 7) << 3));
        *(unsigned long long*)&hhi[idx] = 0ull;
        *(unsigned long long*)&hlo[idx] = 0ull;
    }
    for (int i = tid; i < 1536; i += 256)             // os rows 20-31 cols 0-127 zero
        os[(20 + (i >> 7))*132 + (i & 127)] = 0.f;
    __syncthreads();

    // ---- QKV GEMM: A-frags once, then 6 N-tiles per wave
    {
        bf16x8 ah[2][4], al[2][4];
#pragma unroll
        for (int m = 0; m < 2; ++m) {
            int row = m*16 + l16;
            int asw = (row & 7) << 3;
#pragma unroll
            for (int k = 0; k < 4; ++k) {
                int idx = row*128 + ((k*32 + g16*8) ^ asw);
                ah[m][k] = *(const bf16x8*)&hhi[idx];
                al[m][k] = *(const bf16x8*)&hlo[idx];
            }
        }
        const unsigned short* Wh = wih + (size_t)layer*3*D*D;
        const unsigned short* Wl = wil + (size_t)layer*3*D*D;
#pragma unroll
        for (int nt = 0; nt < 6; ++nt) {
            int n0 = wv*96 + nt*16;
            const unsigned short* rh = Wh + (size_t)(n0 + l16)*D + g16*8;
            const unsigned short* rl = Wl + (size_t)(n0 + l16)*D + g16*8;
            bf16x8 bh[4], bl[4];
#pragma unroll
            for (int k = 0; k < 4; ++k) {
                bh[k] = *(const bf16x8*)(rh + k*32);
                bl[k] = *(const bf16x8*)(rl + k*32);
            }
            float bv = b_in[layer*3*D + n0 + l16];
            f32x4 acc[2];
#pragma unroll
            for (int m = 0; m < 2; ++m) acc[m] = (f32x4){bv,bv,bv,bv};
#pragma unroll
            for (int m = 0; m < 2; ++m)
#pragma unroll
                for (int k = 0; k < 4; ++k) {
                    acc[m] = MFMA_BF16(ah[m][k], bh[k], acc[m], 0, 0, 0);
                    acc[m] = MFMA_BF16(ah[m][k], bl[k], acc[m], 0, 0, 0);
                    acc[m] = MFMA_BF16(al[m][k], bh[k], acc[m], 0, 0, 0);
                }
#pragma unroll
            for (int m = 0; m < 2; ++m)
#pragma unroll
                for (int r = 0; r < 4; ++r) {
                    int row = m*16 + g16*4 + r;
                    if (row < KNN) qkv[row*388 + n0 + l16] = acc[m][r];
                }
        }
    }
    __syncthreads();

    // ---- attention core: thread = (head, t1), float4-vectorized
    if (tid < NH*KNN) {
        int hh = tid / KNN;
        int t1 = tid % KNN;
        int c0 = hh * HD;
        float4 qv[4];
#pragma unroll
        for (int j = 0; j < 4; ++j) qv[j] = *(const float4*)&qkv[t1*388 + c0 + j*4];
        float a[KNN];
        float mx = -3.4e38f;
#pragma unroll
        for (int t2 = 0; t2 < KNN; ++t2) {
            float s = 0.f;
#pragma unroll
            for (int j = 0; j < 4; ++j) {
                float4 kv = *(const float4*)&qkv[t2*388 + 128 + c0 + j*4];
                s += qv[j].x*kv.x + qv[j].y*kv.y + qv[j].z*kv.z + qv[j].w*kv.w;
            }
            s *= 0.25f;
            a[t2] = s;
            mx = fmaxf(mx, s);
        }
        float sum = 0.f;
#pragma unroll
        for (int t2 = 0; t2 < KNN; ++t2) { a[t2] = expf(a[t2]-mx); sum += a[t2]; }
        float inv = 1.0f / sum;
        float4 o[4];
#pragma unroll
        for (int j = 0; j < 4; ++j) o[j] = (float4){0.f,0.f,0.f,0.f};
#pragma unroll
        for (int t2 = 0; t2 < KNN; ++t2) {
            float w = a[t2];
#pragma unroll
            for (int j = 0; j < 4; ++j) {
                float4 vv = *(const float4*)&qkv[t2*388 + 256 + c0 + j*4];
                o[j].x += w*vv.x; o[j].y += w*vv.y; o[j].z += w*vv.z; o[j].w += w*vv.w;
            }
        }
#pragma unroll
        for (int j = 0; j < 4; ++j) {
            float4 ov; ov.x = o[j].x*inv; ov.y = o[j].y*inv;
            ov.z = o[j].z*inv; ov.w = o[j].w*inv;
            *(float4*)&os[t1*132 + c0 + j*4] = ov;
        }
    }
    __syncthreads();

    // ---- out-proj MFMA + residual -> qkv[.][0..127]
    {
        // A-frags from os (fp32 -> split on the fly)
        bf16x8 ah[2][4], al[2][4];
#pragma unroll
        for (int m = 0; m < 2; ++m) {
            int row = m*16 + l16;
#pragma unroll
            for (int k = 0; k < 4; ++k) {
                float tmp[8];
                *(float4*)&tmp[0] = *(const float4*)&os[row*132 + k*32 + g16*8];
                *(float4*)&tmp[4] = *(const float4*)&os[row*132 + k*32 + g16*8 + 4];
                ah[m][k] = pack8(tmp);
                float lo[8];
#pragma unroll
                for (int i = 0; i < 8; ++i) lo[i] = tmp[i] - bf2f((unsigned short)ah[m][k][i]);
                al[m][k] = pack8(lo);
            }
        }
        const unsigned short* Wh = woh + (size_t)layer*D*D;
        const unsigned short* Wl = wol + (size_t)layer*D*D;
#pragma unroll
        for (int nt = 0; nt < 2; ++nt) {
            int n0 = wv*32 + nt*16;
            const unsigned short* rh = Wh + (size_t)(n0 + l16)*D + g16*8;
            const unsigned short* rl = Wl + (size_t)(n0 + l16)*D + g16*8;
            bf16x8 bh[4], bl[4];
#pragma unroll
            for (int k = 0; k < 4; ++k) {
                bh[k] = *(const bf16x8*)(rh + k*32);
                bl[k] = *(const bf16x8*)(rl + k*32);
            }
            float bv = b_out[layer*D + n0 + l16];
            f32x4 acc[2];
#pragma unroll
            for (int m = 0; m < 2; ++m) acc[m] = (f32x4){bv,bv,bv,bv};
#pragma unroll
            for (int m = 0; m < 2; ++m)
#pragma unroll
                for (int k = 0; k < 4; ++k) {
                    acc[m] = MFMA_BF16(ah[m][k], bh[k], acc[m], 0, 0, 0);
                    acc[m] = MFMA_BF16(ah[m][k], bl[k], acc[m], 0, 0, 0);
                    acc[m] = MFMA_BF16(al[m][k], bh[k], acc[m], 0, 0, 0);
                }
            int col = n0 + l16;
#pragma unroll
            for (int m = 0; m < 2; ++m)
#pragma unroll
                for (int r = 0; r < 4; ++r) {
                    int row = m*16 + g16*4 + r;
                    if (row < KNN) {
                        int idx = row*128 + (col ^ ((row & 7) << 3));
                        float res = bf2f(hhi[idx]) + bf2f(hlo[idx]);
                        qkv[row*388 + col] = acc[m][r] + res;
                    }
                }
        }
    }
    __syncthreads();

    // ---- LN1 stats: 8-lane group per token
    if (tid < KNN*8) {
        int t = tid >> 3, j = tid & 7;
        float s = 0.f;
#pragma unroll
        for (int cc = 0; cc < 16; cc += 4) {
            float4 v = *(const float4*)&qkv[t*388 + j*16 + cc];
            s += v.x + v.y + v.z + v.w;
        }
#pragma unroll
        for (int o = 1; o < 8; o <<= 1) s += __shfl_xor(s, o);
        float mu = s * (1.0f/D);
        float vv = 0.f;
#pragma unroll
        for (int cc = 0; cc < 16; cc += 4) {
            float4 v = *(const float4*)&qkv[t*388 + j*16 + cc];
            float a0 = v.x-mu, a1 = v.y-mu, a2 = v.z-mu, a3 = v.w-mu;
            vv += a0*a0 + a1*a1 + a2*a2 + a3*a3;
        }
#pragma unroll
        for (int o = 1; o < 8; o <<= 1) vv += __shfl_xor(vv, o);
        if (j == 0) {
            mu_s[t] = mu;
            rs_s[t] = rsqrtf(vv*(1.0f/D) + EPS);
        }
    }
    __syncthreads();
    for (int i = tid; i < KNN*D; i += 256) {
        int t = i >> 7, c = i & 127;
        h[base + i] = (qkv[t*388+c]-mu_s[t])*rs_s[t]*g1[layer*D+c] + bb1[layer*D+c];
    }
}

// ---------------------------------------------------------------------------
// FFN via split-bf16 MFMA (unchanged, validated).
// ---------------------------------------------------------------------------
#define TOKB 64
__global__ __launch_bounds__(256) void ffn_mfma_kernel(
    float* __restrict__ h,
    const unsigned short* __restrict__ w1h, const unsigned short* __restrict__ w1l,
    const unsigned short* __restrict__ w2h, const unsigned short* __restrict__ w2l,
    const float* __restrict__ b1, const float* __restrict__ b2,
    const float* __restrict__ g2, const float* __restrict__ bb2,
    int layer)
{
    __shared__ __align__(16) unsigned char smem[49152];
    unsigned short* hhi = (unsigned short*)smem;
    unsigned short* hlo = hhi + 64*128;
    unsigned short* fhi = hlo + 64*128;
    unsigned short* flo = fhi + 64*64;
    float* hsf = (float*)smem;

    int tid = threadIdx.x;
    int lane = tid & 63, wv = tid >> 6;
    int l16 = lane & 15, g16 = lane >> 4;
    size_t base = (size_t)blockIdx.x * (TOKB * D);

#pragma unroll
    for (int e = 0; e < 8; ++e) {
        int flat4 = tid + e*256;
        int t = flat4 >> 5;
        int c = (flat4 & 31) << 2;
        float4 v = *(const float4*)&h[base + (size_t)t*D + c];
        unsigned short h0=f2bf(v.x), h1=f2bf(v.y), h2=f2bf(v.z), h3=f2bf(v.w);
        unsigned short l0=f2bf(v.x-bf2f(h0)), l1=f2bf(v.y-bf2f(h1)),
                       l2=f2bf(v.z-bf2f(h2)), l3=f2bf(v.w-bf2f(h3));
        int idx = t*128 + (c ^ ((t & 7) << 3));
        unsigned long long ph = (unsigned long long)h0 | ((unsigned long long)h1<<16)
                              | ((unsigned long long)h2<<32) | ((unsigned long long)h3<<48);
        unsigned long long pl = (unsigned long long)l0 | ((unsigned long long)l1<<16)
                              | ((unsigned long long)l2<<32) | ((unsigned long long)l3<<48);
        *(unsigned long long*)&hhi[idx] = ph;
        *(unsigned long long*)&hlo[idx] = pl;
    }
    __syncthreads();

    const unsigned short* W1h = w1h + (size_t)layer*DFF*D;
    const unsigned short* W1l = w1l + (size_t)layer*DFF*D;
    const unsigned short* W2h = w2h + (size_t)layer*D*DFF;
    const unsigned short* W2l = w2l + (size_t)layer*D*DFF;

    int myf = wv*16 + l16;

    f32x4 acc2[4][2];
#pragma unroll
    for (int m = 0; m < 4; ++m)
#pragma unroll
        for (int j = 0; j < 2; ++j) acc2[m][j] = (f32x4){0.f,0.f,0.f,0.f};

    for (int ft0 = 0; ft0 < DFF; ft0 += 64) {
        float b1v = b1[layer*DFF + ft0 + myf];
        bf16x8 b1f[4][2];
        {
            const unsigned short* r1h = W1h + (size_t)(ft0 + myf)*D + g16*8;
            const unsigned short* r1l = W1l + (size_t)(ft0 + myf)*D + g16*8;
#pragma unroll
            for (int kk = 0; kk < 4; ++kk) {
                b1f[kk][0] = *(const bf16x8*)(r1h + kk*32);
                b1f[kk][1] = *(const bf16x8*)(r1l + kk*32);
            }
        }
        f32x4 acc1[4];
#pragma unroll
        for (int m = 0; m < 4; ++m) acc1[m] = (f32x4){0.f,0.f,0.f,0.f};
#pragma unroll
        for (int m = 0; m < 4; ++m) {
            int arow = m*16 + l16;
            int asw = (arow & 7) << 3;
#pragma unroll
            for (int kk = 0; kk < 4; ++kk) {
                int cc = kk*32 + g16*8;
                int idx = arow*128 + (cc ^ asw);
                bf16x8 ahv = *(const bf16x8*)&hhi[idx];
                bf16x8 alv = *(const bf16x8*)&hlo[idx];
                acc1[m] = MFMA_BF16(ahv, b1f[kk][0], acc1[m], 0, 0, 0);
                acc1[m] = MFMA_BF16(ahv, b1f[kk][1], acc1[m], 0, 0, 0);
                acc1[m] = MFMA_BF16(alv, b1f[kk][0], acc1[m], 0, 0, 0);
            }
        }
        __syncthreads();
#pragma unroll
        for (int m = 0; m < 4; ++m) {
#pragma unroll
            for (int r = 0; r < 4; ++r) {
                int t = m*16 + g16*4 + r;
                float val = fmaxf(acc1[m][r] + b1v, 0.f);
                unsigned short vh = f2bf(val);
                unsigned short vl = f2bf(val - bf2f(vh));
                int idx = t*64 + (myf ^ ((t & 7) << 3));
                fhi[idx] = vh;
                flo[idx] = vl;
            }
        }
        __syncthreads();
        bf16x8 b2f[2][2][2];
#pragma unroll
        for (int j = 0; j < 2; ++j) {
            int d = wv*32 + j*16 + l16;
            const unsigned short* r2h = W2h + (size_t)d*DFF + ft0 + g16*8;
            const unsigned short* r2l = W2l + (size_t)d*DFF + ft0 + g16*8;
#pragma unroll
            for (int kk2 = 0; kk2 < 2; ++kk2) {
                b2f[j][kk2][0] = *(const bf16x8*)(r2h + kk2*32);
                b2f[j][kk2][1] = *(const bf16x8*)(r2l + kk2*32);
            }
        }
#pragma unroll
        for (int m = 0; m < 4; ++m) {
            int arow = m*16 + l16;
            int asw = (arow & 7) << 3;
#pragma unroll
            for (int kk2 = 0; kk2 < 2; ++kk2) {
                int fo = kk2*32 + g16*8;
                int idx = arow*64 + (fo ^ asw);
                bf16x8 ahv = *(const bf16x8*)&fhi[idx];
                bf16x8 alv = *(const bf16x8*)&flo[idx];
#pragma unroll
                for (int j = 0; j < 2; ++j) {
                    acc2[m][j] = MFMA_BF16(ahv, b2f[j][kk2][0], acc2[m][j], 0, 0, 0);
                    acc2[m][j] = MFMA_BF16(ahv, b2f[j][kk2][1], acc2[m][j], 0, 0, 0);
                    acc2[m][j] = MFMA_BF16(alv, b2f[j][kk2][0], acc2[m][j], 0, 0, 0);
                }
            }
        }
    }

    float val[4][2][4];
#pragma unroll
    for (int j = 0; j < 2; ++j) {
        int d = wv*32 + j*16 + l16;
        float bb = b2[layer*D + d];
#pragma unroll
        for (int m = 0; m < 4; ++m) {
#pragma unroll
            for (int r = 0; r < 4; ++r) {
                int t = m*16 + g16*4 + r;
                int idx = t*128 + (d ^ ((t & 7) << 3));
                float res = bf2f(hhi[idx]) + bf2f(hlo[idx]);
                val[m][j][r] = acc2[m][j][r] + bb + res;
            }
        }
    }
    __syncthreads();
#pragma unroll
    for (int j = 0; j < 2; ++j) {
        int d = wv*32 + j*16 + l16;
#pragma unroll
        for (int m = 0; m < 4; ++m)
#pragma unroll
            for (int r = 0; r < 4; ++r) {
                int t = m*16 + g16*4 + r;
                hsf[t*132 + d] = val[m][j][r];
            }
    }
    __syncthreads();
    {
        int tt = tid >> 2, part = tid & 3;
        const float* row = &hsf[tt*132 + part*32];
        float s = 0.f;
#pragma unroll
        for (int i = 0; i < 32; i += 4) {
            float4 v4 = *(const float4*)&row[i];
            s += v4.x + v4.y + v4.z + v4.w;
        }
        s += __shfl_xor(s, 1); s += __shfl_xor(s, 2);
        float mu = s * (1.f/128.f);
        float vv = 0.f;
#pragma unroll
        for (int i = 0; i < 32; i += 4) {
            float4 v4 = *(const float4*)&row[i];
            float a0 = v4.x-mu, a1 = v4.y-mu, a2 = v4.z-mu, a3 = v4.w-mu;
            vv += a0*a0 + a1*a1 + a2*a2 + a3*a3;
        }
        vv += __shfl_xor(vv, 1); vv += __shfl_xor(vv, 2);
        float rs = rsqrtf(vv*(1.f/128.f) + EPS);
        const float* G  = g2  + layer*D + part*32;
        const float* Bt = bb2 + layer*D + part*32;
        float* O = &h[base + (size_t)tt*D + part*32];
#pragma unroll
        for (int i = 0; i < 32; i += 4) {
            float4 v4 = *(const float4*)&row[i];
            float4 gg = *(const float4*)&G[i];
            float4 bt = *(const float4*)&Bt[i];
            float4 o;
            o.x = (v4.x-mu)*rs*gg.x + bt.x;
            o.y = (v4.y-mu)*rs*gg.y + bt.y;
            o.z = (v4.z-mu)*rs*gg.z + bt.z;
            o.w = (v4.w-mu)*rs*gg.w + bt.w;
            *(float4*)&O[i] = o;
        }
    }
}

// ---------------------------------------------------------------------------
// Final linear (unchanged).
// ---------------------------------------------------------------------------
__global__ __launch_bounds__(256) void final_kernel(
    const float* __restrict__ h, const float* __restrict__ lw,
    const float* __restrict__ lb, float* __restrict__ out)
{
    __shared__ float hr[4][KNN*D];
    int g0 = blockIdx.x * 4;
    int tid = threadIdx.x;
    for (int i = tid; i < 4*KNN*D; i += 256)
        hr[i / (KNN*D)][i % (KNN*D)] = h[(size_t)g0*KNN*D + i];
    __syncthreads();

    int d = tid & 127;
    int s = tid >> 7;
    const float* W = lw + (size_t)d * (KNN*D);
    float acc0 = lb[d], acc1 = lb[d];
#pragma unroll 4
    for (int j = 0; j < KNN*D; j += 4) {
        float4 wv = *(const float4*)&W[j];
        float4 h0 = *(const float4*)&hr[s][j];
        float4 h1 = *(const float4*)&hr[s+2][j];
        acc0 += h0.x*wv.x + h0.y*wv.y + h0.z*wv.z + h0.w*wv.w;
        acc1 += h1.x*wv.x + h1.y*wv.y + h1.z*wv.z + h1.w*wv.w;
    }
    out[(size_t)(g0+s)*D + d]   = acc0;
    out[(size_t)(g0+s+2)*D + d] = acc1;
}

// ---------------------------------------------------------------------------
extern "C" void kernel_launch(void* const* d_in, const int* in_sizes, int n_in,
                              void* d_out, int out_size, void* d_ws, size_t ws_size,
                              hipStream_t stream)
{
    const float* x     = (const float*)d_in[0];
    const float* pc    = (const float*)d_in[1];
    const float* query = (const float*)d_in[2];
    const float* ckw   = (const float*)d_in[3];
    const float* ckb   = (const float*)d_in[4];
    const float* cbw   = (const float*)d_in[5];
    const float* cbb   = (const float*)d_in[6];
    const float* w_in  = (const float*)d_in[7];
    const float* b_in  = (const float*)d_in[8];
    const float* w_out = (const float*)d_in[9];
    const float* b_out = (const float*)d_in[10];
    const float* w1    = (const float*)d_in[11];
    const float* b1    = (const float*)d_in[12];
    const float* w2    = (const float*)d_in[13];
    const float* b2    = (const float*)d_in[14];
    const float* g1    = (const float*)d_in[15];
    const float* bb1   = (const float*)d_in[16];
    const float* g2    = (const float*)d_in[17];
    const float* bb2   = (const float*)d_in[18];
    const float* lw    = (const float*)d_in[19];
    const float* lb    = (const float*)d_in[20];
    float* out = (float*)d_out;

    char* ws = (char*)d_ws;
    int*   idx = (int*)ws;                                   // 163,840 B
    float* dis = (float*)(ws + 163840);                      // 163,840 B
    float* h   = (float*)(ws + 327680);                      // 20,971,520 B
    unsigned short* w1hp = (unsigned short*)(ws + 21299200);
    unsigned short* w1lp = (unsigned short*)(ws + 21299200 + 1572864);
    unsigned short* w2hp = (unsigned short*)(ws + 21299200 + 2*1572864);
    unsigned short* w2lp = (unsigned short*)(ws + 21299200 + 3*1572864);
    unsigned short* wihp = (unsigned short*)(ws + 27590656);
    unsigned short* wilp = (unsigned short*)(ws + 27590656 + 294912);
    unsigned short* wohp = (unsigned short*)(ws + 27590656 + 2*294912);
    unsigned short* wolp = (unsigned short*)(ws + 27590656 + 2*294912 + 98304);
    // total ws use: 28,377,088 B

    knn_kernel <<<NSEQ/4, 256, 0, stream>>>(pc, query, idx, dis);
    pool_kernel<<<NSEQ,   256, 0, stream>>>(x, pc, query, ckw, ckb, cbw, cbb,
                                            idx, dis, h);
    prep_kernel<<<(NL*DFF*D)/256, 256, 0, stream>>>(
        w1, w2, w_in, w_out, w1hp, w1lp, w2hp, w2lp, wihp, wilp, wohp, wolp);
    for (int l = 0; l < NL; ++l) {
        attn_mfma_kernel<<<NSEQ, 256, 0, stream>>>(
            h, wihp, wilp, wohp, wolp, b_in, b_out, g1, bb1, l);
        ffn_mfma_kernel<<<(NSEQ*KNN)/TOKB, 256, 0, stream>>>(
            h, w1hp, w1lp, w2hp, w2lp, b1, b2, g2, bb2, l);
    }
    final_kernel<<<NSEQ/4, 256, 0, stream>>>(h, lw, lb, out);
}